// Round 9
// baseline (168.369 us; speedup 1.0000x reference)
//
#include <hip/hip_runtime.h>

// SparseNodeConv: out = segment_sum((X@W)[edge_dst] by edge_src) + X@R + bias
// Strategy: AX = segment_sum(X[dst] by src)  (aggregate RAW features, linearity)
//           out = [AX | X](bf16) @ [W; R](bf16) + bias   via MFMA 16x16x32 bf16
//
// Pipeline (6 dispatches incl. memset):
//  k_convhist: X f32 -> Xb bf16 (row-major)  +  coarse K-bucket histogram.
//  k_bucket  : in-block 2-chunk scan of ccnt -> cbs; per-2048-edge LDS
//              counting sort -> bucket-contiguous packs (atomic reservation
//              on zero-initialized cursor0). 782 blocks (~3/CU).
//  k_fine    : one block per bucket (K=391, ~1.5/CU): in-block scan -> beg;
//              LDS per-node hist+scan -> per-node CSR offs + exact scatter
//              (ushort dst, writes confined to 8KB L2-local window).
//  k_agg     : gather-sum. lane quarter q handles edge j+q, 16 lanes x 16B
//              cover one 256B row -> 4 edges per VMEM instr; unroll 4 ->
//              16 rows in flight per lane. Cross-quarter reduce per NODE.
//  k_gemm    : [AX|X] @ [W;R] + bias, MFMA 16x16x32 bf16.
// N = 50000, E = 1600000, D = 128. Assumes N < 65536 (dst fits 16 bits)
// and K <= 512 coarse buckets (N <= 65536 with BSH=7).

typedef __attribute__((ext_vector_type(8))) short bf16x8;
typedef __attribute__((ext_vector_type(4))) float f32x4;

#define BSH 7      // coarse bucket = 128 nodes
#define CHUNK 2048 // edges per k_bucket block

__device__ __forceinline__ unsigned f2bf(float f) {
  unsigned u = __float_as_uint(f);
  return (u + 0x7fffu + ((u >> 16) & 1u)) >> 16;  // RNE
}
__device__ __forceinline__ unsigned pack2(float lo, float hi) {
  return f2bf(lo) | (f2bf(hi) << 16);
}
__device__ __forceinline__ float bflo(unsigned v) { return __uint_as_float(v << 16); }
__device__ __forceinline__ float bfhi(unsigned v) { return __uint_as_float(v & 0xffff0000u); }

// ---------- fused: X (f32) -> Xb (bf16 u32 pairs) + coarse histogram ----------
__global__ __launch_bounds__(256) void k_convhist(const float4* __restrict__ X,
                                                  uint2* __restrict__ Xb, int n4,
                                                  const int* __restrict__ src,
                                                  int* __restrict__ ccnt,
                                                  int E_, int K_) {
  __shared__ int h[512];
  h[threadIdx.x] = 0;
  h[threadIdx.x + 256] = 0;
  __syncthreads();
  int stride = gridDim.x * blockDim.x;
  int gtid = blockIdx.x * blockDim.x + threadIdx.x;
  for (int i = gtid; i < n4; i += stride) {
    float4 v = X[i];
    uint2 o;
    o.x = pack2(v.x, v.y);
    o.y = pack2(v.z, v.w);
    Xb[i] = o;
  }
  for (int i = gtid; i < E_; i += stride)
    atomicAdd(&h[((unsigned)src[i]) >> BSH], 1);
  __syncthreads();
  for (int b = threadIdx.x; b < K_; b += 256) {
    int c = h[b];
    if (c > 0) atomicAdd(&ccnt[b], c);
  }
}

// ---------- scan helpers ----------
__device__ __forceinline__ int incl_scan256(int v, int tid) {
  int lane = tid & 63, w = tid >> 6;
  int x = v;
#pragma unroll
  for (int d = 1; d < 64; d <<= 1) {
    int o = __shfl_up(x, d, 64);
    if (lane >= d) x += o;
  }
  __shared__ int wsum[4];
  if (lane == 63) wsum[w] = x;
  __syncthreads();
  if (w > 0) x += wsum[0];
  if (w > 1) x += wsum[1];
  if (w > 2) x += wsum[2];
  return x;
}

// exclusive scan of ccnt[0..K) into shared cbs[]; cbs[K] = E. K <= 512.
__device__ __forceinline__ void scan_ccnt(const int* __restrict__ ccnt,
                                          int* cbs, int K_, int E_, int tid) {
  int v = (tid < K_) ? ccnt[tid] : 0;
  int s1 = incl_scan256(v, tid);
  cbs[tid] = s1 - v;
  __shared__ int carry;
  if (tid == 255) carry = s1;
  __syncthreads();
  int t2 = 256 + tid;
  int v2 = (t2 < K_) ? ccnt[t2] : 0;
  int s2 = incl_scan256(v2, tid);
  cbs[t2] = s2 - v2 + carry;
  if (tid == 0 && K_ < 256) cbs[K_] = E_;  // K>=256 covered by t2 path
  __syncthreads();
}

// ---------- pass A: coarse scatter into 128-node buckets ----------
// pack = (src&127)<<16 | dst   (dst < 65536)
__global__ __launch_bounds__(256) void k_bucket(const int* __restrict__ src,
                                                const int* __restrict__ dst,
                                                const int* __restrict__ ccnt,
                                                int* __restrict__ cursor0,
                                                unsigned* __restrict__ packs,
                                                int E_, int K_) {
  __shared__ int cbs[512];
  __shared__ int lcnt[512];
  __shared__ int lbase[512];
  __shared__ unsigned lsrc[CHUNK];
  __shared__ unsigned ldst[CHUNK];
  int tid = threadIdx.x;
  scan_ccnt(ccnt, cbs, K_, E_, tid);
  lcnt[tid] = 0;
  lcnt[tid + 256] = 0;
  __syncthreads();
  int base = blockIdx.x * CHUNK;
  int n = min(CHUNK, E_ - base);
  for (int i = tid; i < n; i += 256) {
    unsigned s = (unsigned)src[base + i];
    unsigned d = (unsigned)dst[base + i];
    lsrc[i] = s;
    ldst[i] = d;
    atomicAdd(&lcnt[s >> BSH], 1);
  }
  __syncthreads();
  for (int b = tid; b < K_; b += 256) {
    int c = lcnt[b];
    int r = (c > 0) ? atomicAdd(&cursor0[b], c) : 0;
    lbase[b] = cbs[b] + r;
    lcnt[b] = 0;  // reuse as local rank cursor
  }
  __syncthreads();
  for (int i = tid; i < n; i += 256) {
    unsigned s = lsrc[i], d = ldst[i];
    int b = s >> BSH;
    int r = atomicAdd(&lcnt[b], 1);
    packs[lbase[b] + r] = ((s & 127u) << 16) | d;
  }
}

// ---------- pass B: per-node hist + scan + fine scatter + offs write ----------
__global__ __launch_bounds__(256) void k_fine(const int* __restrict__ ccnt,
                                              const unsigned* __restrict__ packs,
                                              unsigned short* __restrict__ sdst,
                                              int* __restrict__ offs,
                                              int N_, int E_, int K_) {
  __shared__ int cbs[512];
  __shared__ int lcnt[256];
  __shared__ int lbase[256];
  int tid = threadIdx.x;
  int b = blockIdx.x;
  scan_ccnt(ccnt, cbs, K_, E_, tid);
  int beg = cbs[b];
  int n = cbs[b + 1] - beg;  // this bucket's edge count
  int nodeBase = b << BSH;
  int nNodes = min(1 << BSH, N_ - nodeBase);
  lcnt[tid] = 0;
  __syncthreads();
  // per-node histogram (LDS atomics); sl in [0,128)
  for (int i = tid; i < n; i += 256) atomicAdd(&lcnt[packs[beg + i] >> 16], 1);
  __syncthreads();
  int v = lcnt[tid];
  int incl = incl_scan256(v, tid);
  int excl = incl - v;
  lbase[tid] = excl;
  if (tid < nNodes) offs[nodeBase + tid] = beg + excl;
  if (b == gridDim.x - 1 && tid == 0) offs[N_] = E_;
  __syncthreads();
  lcnt[tid] = 0;  // reuse as fine cursor
  __syncthreads();
  for (int i = tid; i < n; i += 256) {
    unsigned p = packs[beg + i];
    int sl = p >> 16;
    int r = atomicAdd(&lcnt[sl], 1);
    sdst[beg + lbase[sl] + r] = (unsigned short)(p & 0xffffu);
  }
}

// ---------- aggregation: AXb[i] = sum over CSR segment i of Xb[dst] ----------
// one wave = one node; quarter q = edge j+q; 16 lanes x uint4 = one 256B row.
__global__ __launch_bounds__(256) void k_agg(const uint4* __restrict__ Xb4,
                                             const int* __restrict__ offs,
                                             const unsigned short* __restrict__ sdst,
                                             uint4* __restrict__ AXb4, int N_) {
  int node = (blockIdx.x * 256 + threadIdx.x) >> 6;
  if (node >= N_) return;
  int lane = threadIdx.x & 63;
  int q = lane >> 4, c = lane & 15;
  int beg = offs[node], end = offs[node + 1];
  float a0 = 0.f, a1 = 0.f, a2 = 0.f, a3 = 0.f;
  float a4 = 0.f, a5 = 0.f, a6 = 0.f, a7 = 0.f;
  int j = beg;
#pragma unroll 4
  for (; j + 4 <= end; j += 4) {
    int e = sdst[j + q];
    uint4 v = Xb4[(size_t)e * 16 + c];
    a0 += bflo(v.x); a1 += bfhi(v.x);
    a2 += bflo(v.y); a3 += bfhi(v.y);
    a4 += bflo(v.z); a5 += bfhi(v.z);
    a6 += bflo(v.w); a7 += bfhi(v.w);
  }
  if (j + q < end) {  // tail (16-lane-group-uniform predicate)
    int e = sdst[j + q];
    uint4 v = Xb4[(size_t)e * 16 + c];
    a0 += bflo(v.x); a1 += bfhi(v.x);
    a2 += bflo(v.y); a3 += bfhi(v.y);
    a4 += bflo(v.z); a5 += bfhi(v.z);
    a6 += bflo(v.w); a7 += bfhi(v.w);
  }
  // cross-quarter reduce (once per node)
  a0 += __shfl_xor(a0, 16, 64); a1 += __shfl_xor(a1, 16, 64);
  a2 += __shfl_xor(a2, 16, 64); a3 += __shfl_xor(a3, 16, 64);
  a4 += __shfl_xor(a4, 16, 64); a5 += __shfl_xor(a5, 16, 64);
  a6 += __shfl_xor(a6, 16, 64); a7 += __shfl_xor(a7, 16, 64);
  a0 += __shfl_xor(a0, 32, 64); a1 += __shfl_xor(a1, 32, 64);
  a2 += __shfl_xor(a2, 32, 64); a3 += __shfl_xor(a3, 32, 64);
  a4 += __shfl_xor(a4, 32, 64); a5 += __shfl_xor(a5, 32, 64);
  a6 += __shfl_xor(a6, 32, 64); a7 += __shfl_xor(a7, 32, 64);
  if (q == 0) {
    uint4 o;
    o.x = pack2(a0, a1);
    o.y = pack2(a2, a3);
    o.z = pack2(a4, a5);
    o.w = pack2(a6, a7);
    AXb4[(size_t)node * 16 + c] = o;
  }
}

// ---------- GEMM: out[N,128] = AXb@W + Xb@R + bias (MFMA 16x16x32 bf16) ----------
__global__ __launch_bounds__(256) void k_gemm(const unsigned* __restrict__ AXb,
                                              const unsigned* __restrict__ Xb,
                                              const float* __restrict__ Wg,
                                              const float* __restrict__ Rg,
                                              const float* __restrict__ bias,
                                              float* __restrict__ out, int N_) {
  __shared__ __align__(16) unsigned short Bt[128][136];
  int tid = threadIdx.x;
  int wave = tid >> 6, lane = tid & 63;
  int r = lane & 15, g = lane >> 4;
  int rowBase = (blockIdx.x * 4 + wave) * 16;
  int arow = rowBase + r;
  if (arow >= N_) arow = 0;  // clamp; stores are guarded

  bf16x8 fa[4], fx[4];
  const bf16x8* pA = (const bf16x8*)(AXb + (size_t)arow * 64);
  const bf16x8* pX = (const bf16x8*)(Xb + (size_t)arow * 64);
#pragma unroll
  for (int kk = 0; kk < 4; ++kk) {
    fa[kk] = pA[kk * 4 + g];
    fx[kk] = pX[kk * 4 + g];
  }

  f32x4 acc[8];
#pragma unroll
  for (int n = 0; n < 8; ++n) acc[n] = (f32x4){0.f, 0.f, 0.f, 0.f};

  for (int e = tid; e < 128 * 32; e += 256) {
    int c4 = (e & 31) * 4;
    int k = e >> 5;
    float4 v = *(const float4*)&Wg[k * 128 + c4];
    Bt[c4 + 0][k] = (unsigned short)f2bf(v.x);
    Bt[c4 + 1][k] = (unsigned short)f2bf(v.y);
    Bt[c4 + 2][k] = (unsigned short)f2bf(v.z);
    Bt[c4 + 3][k] = (unsigned short)f2bf(v.w);
  }
  __syncthreads();
#pragma unroll
  for (int n = 0; n < 8; ++n) {
    int col = n * 16 + r;
#pragma unroll
    for (int kk = 0; kk < 4; ++kk) {
      bf16x8 fb = *(const bf16x8*)&Bt[col][kk * 32 + g * 8];
      acc[n] = __builtin_amdgcn_mfma_f32_16x16x32_bf16(fa[kk], fb, acc[n], 0, 0, 0);
    }
  }
  __syncthreads();

  for (int e = tid; e < 128 * 32; e += 256) {
    int c4 = (e & 31) * 4;
    int k = e >> 5;
    float4 v = *(const float4*)&Rg[k * 128 + c4];
    Bt[c4 + 0][k] = (unsigned short)f2bf(v.x);
    Bt[c4 + 1][k] = (unsigned short)f2bf(v.y);
    Bt[c4 + 2][k] = (unsigned short)f2bf(v.z);
    Bt[c4 + 3][k] = (unsigned short)f2bf(v.w);
  }
  __syncthreads();
#pragma unroll
  for (int n = 0; n < 8; ++n) {
    int col = n * 16 + r;
#pragma unroll
    for (int kk = 0; kk < 4; ++kk) {
      bf16x8 fb = *(const bf16x8*)&Bt[col][kk * 32 + g * 8];
      acc[n] = __builtin_amdgcn_mfma_f32_16x16x32_bf16(fx[kk], fb, acc[n], 0, 0, 0);
    }
  }

#pragma unroll
  for (int n = 0; n < 8; ++n) {
    int col = n * 16 + r;
    float bv = bias[col];
#pragma unroll
    for (int jj = 0; jj < 4; ++jj) {
      int row = rowBase + g * 4 + jj;
      if (row < N_) out[(size_t)row * 128 + col] = acc[n][jj] + bv;
    }
  }
}

extern "C" void kernel_launch(void* const* d_in, const int* in_sizes, int n_in,
                              void* d_out, int out_size, void* d_ws, size_t ws_size,
                              hipStream_t stream) {
  const float* X = (const float*)d_in[0];
  const int* esrc = (const int*)d_in[1];
  const int* edst = (const int*)d_in[2];
  const float* Wg = (const float*)d_in[3];
  const float* Rg = (const float*)d_in[4];
  const float* bias = (const float*)d_in[5];
  float* out = (float*)d_out;

  int ND = in_sizes[0];  // N*D
  int E = in_sizes[1];
  int N = ND / 128;
  int K = (N + (1 << BSH) - 1) >> BSH;  // 391 coarse buckets

  char* ws = (char*)d_ws;
  size_t off = 0;
  auto wsalloc = [&](size_t b) {
    char* p = ws + off;
    off = (off + b + 255) & ~(size_t)255;
    return p;
  };
  int* offs = (int*)wsalloc((size_t)(N + 1) * 4);
  unsigned short* sdst = (unsigned short*)wsalloc((size_t)E * 2);
  unsigned* Xb = (unsigned*)wsalloc((size_t)N * 64 * 4);
  unsigned* AXb = (unsigned*)wsalloc((size_t)N * 64 * 4);
  // transient aliases inside the AXb region (dead before k_agg writes AXb):
  unsigned* packs = AXb;                       // E u32 (6.4MB <= 12.8MB)
  int* ccnt = (int*)(AXb + (size_t)E);         // 512 ints (K used)
  int* cursor0 = ccnt + 512;                   // 512 ints (K used)

  int nchunk = (E + CHUNK - 1) / CHUNK;
  hipMemsetAsync(ccnt, 0, 1024 * 4, stream);  // ccnt + cursor0
  k_convhist<<<1024, 256, 0, stream>>>((const float4*)X, (uint2*)Xb, ND / 4,
                                       esrc, ccnt, E, K);
  k_bucket<<<nchunk, 256, 0, stream>>>(esrc, edst, ccnt, cursor0, packs, E, K);
  k_fine<<<K, 256, 0, stream>>>(ccnt, packs, sdst, offs, N, E, K);
  k_agg<<<(N + 3) / 4, 256, 0, stream>>>((const uint4*)Xb, offs, sdst,
                                         (uint4*)AXb, N);
  k_gemm<<<(N + 63) / 64, 256, 0, stream>>>(AXb, Xb, Wg, Rg, bias, out, N);
}